// Round 10
// baseline (121.771 us; speedup 1.0000x reference)
//
#include <hip/hip_runtime.h>
#include <hip/hip_bf16.h>

typedef unsigned short u16;
typedef __attribute__((ext_vector_type(4))) int   i32x4;
typedef __attribute__((ext_vector_type(4))) float f32x4;

constexpr int N = 8192;
constexpr int D = 1024;
constexpr float INVT = 1.0f / 0.07f;
constexpr int BK = 64;                         // i8 k per tile
constexpr int KT = D / BK;                     // 16 K-tiles
constexpr int NBLK = 64;                       // 8192 / 128 row-blocks
constexpr int NTRI = NBLK * (NBLK + 1) / 2;    // 2080 lower-tri tiles
constexpr int PANEL_BYTES = 128 * 1024;        // 128 rows x 1024 i8

// ---- workspace layout (bytes) ----
// q8 is stored TILED: panel p (128 rows), slot s (16 i8 of k), row r:
//   byte = p*131072 + s*2048 + r*16  -> one K-tile (4 slots) = 8KB contiguous
//   AND an MFMA fragment read (16-lane group, consecutive rows) = 256B
//   contiguous -> fragments are directly coalesced global loads.
constexpr size_t OFF_Q8    = 0;                      // N*D i8 = 8 MiB (tiled)
constexpr size_t OFF_SUME  = 8388608;                // N f32 (32 KiB)
constexpr size_t OFF_POSS  = OFF_SUME + 32768;       // N f32
constexpr size_t OFF_TYPE  = OFF_POSS + 32768;       // N i32
constexpr size_t OFF_SCALE = OFF_TYPE + 32768;       // N f32

// one wave per row: normalize, per-row absmax, quantize to i8 into the
// TILED q8 layout. Also zeroes sum_exp/pos_sum (replaces k_zero).
__global__ __launch_bounds__(256) void k_norm(
    const float* __restrict__ feat, const long long* __restrict__ et,
    signed char* __restrict__ q8, float* __restrict__ scales,
    int* __restrict__ types,
    float* __restrict__ sum_exp, float* __restrict__ pos_sum) {
  if (threadIdx.x < 4)
    sum_exp[blockIdx.x * 4 + threadIdx.x] = 0.f;
  else if (threadIdx.x < 8)
    pos_sum[blockIdx.x * 4 + threadIdx.x - 4] = 0.f;

  const int row = blockIdx.x * 4 + (threadIdx.x >> 6);
  const int l = threadIdx.x & 63;
  const float4* src = (const float4*)(feat + (size_t)row * D);
  float4 v[4];
  float ss = 0.f, ma = 0.f;
  #pragma unroll
  for (int c = 0; c < 4; ++c) {
    v[c] = src[c * 64 + l];
    ss += v[c].x * v[c].x + v[c].y * v[c].y + v[c].z * v[c].z + v[c].w * v[c].w;
    ma = fmaxf(ma, fmaxf(fmaxf(fabsf(v[c].x), fabsf(v[c].y)),
                         fmaxf(fabsf(v[c].z), fabsf(v[c].w))));
  }
  #pragma unroll
  for (int m = 32; m; m >>= 1) {
    ss += __shfl_xor(ss, m);
    ma = fmaxf(ma, __shfl_xor(ma, m));
  }
  const float sc = 1.0f / fmaxf(sqrtf(ss), 1e-12f);
  const float man = ma * sc;                       // normalized row absmax
  const float invq = 127.0f / fmaxf(man, 1e-30f);  // f_norm -> i8
  const float qf = sc * invq;
  // tiled write: word w = c*64+l (k-ints) -> slot s = w>>2, byte (w&3)*4.
  signed char* pb = q8 + (size_t)(row >> 7) * PANEL_BYTES + (row & 127) * 16;
  #pragma unroll
  for (int c = 0; c < 4; ++c) {
    const int b0 = (unsigned char)(signed char)__float2int_rn(v[c].x * qf);
    const int b1 = (unsigned char)(signed char)__float2int_rn(v[c].y * qf);
    const int b2 = (unsigned char)(signed char)__float2int_rn(v[c].z * qf);
    const int b3 = (unsigned char)(signed char)__float2int_rn(v[c].w * qf);
    const int w = c * 64 + l;
    *(int*)(pb + (w >> 2) * 2048 + (w & 3) * 4) =
        b0 | (b1 << 8) | (b2 << 16) | (b3 << 24);
  }
  if (l == 0) {
    scales[row] = man / 127.0f;                    // sim = acc*s_i*s_j
    types[row] = (int)et[row];
  }
}

__device__ __forceinline__ void mfma_i8(i32x4& d, i32x4 a, i32x4 b) {
  asm volatile("v_mfma_i32_16x16x64_i8 %0, %1, %2, %0"
               : "+v"(d) : "v"(a), "v"(b));
}

// 128x128 lower-tri tiles of sim = (q8 . q8^T) * s_i * s_j / T.
// BARRIER-FREE K-loop: the tiled q8 layout makes each wave's MFMA
// fragments directly coalesced global loads (256B per 16-lane group), so
// LDS staging -- and with it every K-loop s_barrier / vmcnt(0) drain, the
// convoy that held MfmaUtil at 10-13% across r5-r9 -- is deleted. Each
// wave double-buffers 2 K-tiles of fragments in registers; the compiler
// schedules counted vmcnt waits per register set; ~12 independent
// waves/CU hide loaded-L2 latency via TLP (m114 mechanism). LDS holds
// only the type/scale tables (one prologue barrier).
__global__ __launch_bounds__(256) void k_gemm(
    const signed char* __restrict__ q8, const float* __restrict__ scales,
    const int* __restrict__ types,
    float* __restrict__ sum_exp, float* __restrict__ pos_sum) {
  __shared__ int rt[128], ct[128];
  __shared__ float rsl[128], csl[128];

  // ---- tile decode: XCD x (= pid%8, HW round-robin), local index l ----
  const int pid = blockIdx.x;
  const int x = pid & 7;
  const int l = pid >> 3;                       // 0..259
  int cbs[8];
  #pragma unroll
  for (int j = 0; j < 8; ++j) cbs[j] = 8 * j + ((j & 1) ? 7 - x : x);
  int lo = 0, hi = 63;
  while (lo < hi) {
    const int mid = (lo + hi + 1) >> 1;
    int T = 0;
    #pragma unroll
    for (int j = 0; j < 8; ++j) T += max(0, mid - cbs[j]);
    if (T <= l) lo = mid; else hi = mid - 1;
  }
  const int rb = lo;
  int Tr = 0;
  #pragma unroll
  for (int j = 0; j < 8; ++j) Tr += max(0, rb - cbs[j]);
  const int rem = l - Tr;                       // 0..7: index into cb prefix
  int cb = 0;
  #pragma unroll
  for (int j = 0; j < 8; ++j) if (j == rem) cb = cbs[j];

  const int brow = rb * 128, bcol = cb * 128;
  const bool diag = (rb == cb);

  const int tid = threadIdx.x;
  const int lane = tid & 63;
  const int wid = tid >> 6;
  const int wr = wid >> 1, wc = wid & 1;

  if (tid < 128) {
    rt[tid] = types[brow + tid];
    rsl[tid] = scales[brow + tid] * INVT;   // fold 1/T into row scale
  } else {
    ct[tid - 128] = types[bcol + tid - 128];
    csl[tid - 128] = scales[bcol + tid - 128];
  }
  __syncthreads();                          // tables published; last barrier

  i32x4 acc[4][4];
  #pragma unroll
  for (int i = 0; i < 4; ++i)
    #pragma unroll
    for (int j = 0; j < 4; ++j) acc[i][j] = (i32x4){0, 0, 0, 0};

  // fragment base: lane supplies row (lane&15) of its sub-tile, k-slot
  // lane>>4; global byte = panel + (slot*128 + row)*16 (+ mi*16 rows).
  const int slotR = lane >> 4;
  const int arow = wr * 64 + (lane & 15);
  const int brw  = wc * 64 + (lane & 15);
  const signed char* pA =
      q8 + (size_t)rb * PANEL_BYTES + (slotR * 128 + arow) * 16;
  const signed char* pB =
      q8 + (size_t)cb * PANEL_BYTES + (slotR * 128 + brw) * 16;

  i32x4 a0[4], b0[4], a1[4], b1[4];

  #define LOADP(tt, A, B) {                                           \
    const int o = (tt) * 8192;                                        \
    _Pragma("unroll")                                                 \
    for (int q = 0; q < 4; ++q) {                                     \
      A[q] = *(const i32x4*)(pA + o + q * 256);                       \
      B[q] = *(const i32x4*)(pB + o + q * 256);                       \
    } }

  #define MFMAP(A, B) {                                               \
    __builtin_amdgcn_s_setprio(1);                                    \
    _Pragma("unroll")                                                 \
    for (int mi = 0; mi < 4; ++mi)                                    \
      _Pragma("unroll")                                               \
      for (int ni = 0; ni < 4; ++ni) mfma_i8(acc[mi][ni], A[mi], B[ni]); \
    __builtin_amdgcn_s_setprio(0);                                    \
  }

  LOADP(0, a0, b0)
  LOADP(1, a1, b1)
  for (int t = 0; t < KT; t += 2) {
    MFMAP(a0, b0)
    if (t + 2 < KT) LOADP(t + 2, a0, b0)   // overwrite after consumption
    MFMAP(a1, b1)
    if (t + 3 < KT) LOADP(t + 3, a1, b1)
  }

  // MFMA -> VALU read hazard guard (inline-asm MFMA opaque to hazard recog.)
  asm volatile("s_nop 7\n\ts_nop 7\n\ts_nop 7");
  #pragma unroll
  for (int i = 0; i < 4; ++i)
    #pragma unroll
    for (int j = 0; j < 4; ++j) asm volatile("" : "+v"(acc[i][j]));

  // epilogue: C/D layout col = lane&15, row = (lane>>4)*4 + reg  [m89]
  const int csub = lane & 15;
  const int rsub = (lane >> 4) * 4;
  int gcolv[4], ctv[4];
  float cfv[4];
  #pragma unroll
  for (int ni = 0; ni < 4; ++ni) {
    const int cl = wc * 64 + ni * 16 + csub;
    gcolv[ni] = bcol + cl;
    ctv[ni] = ct[cl];
    cfv[ni] = csl[cl];
  }
  float cse[4] = {0.f, 0.f, 0.f, 0.f};
  float cps[4] = {0.f, 0.f, 0.f, 0.f};

  #pragma unroll
  for (int mi = 0; mi < 4; ++mi) {
    #pragma unroll
    for (int r = 0; r < 4; ++r) {
      const int rl = wr * 64 + mi * 16 + rsub + r;
      const int grow = brow + rl;
      const int rty = rt[rl];
      const float rfac = rsl[rl];                 // includes 1/T
      float se = 0.f, ps = 0.f;
      #pragma unroll
      for (int ni = 0; ni < 4; ++ni) {
        const float s = (float)acc[mi][ni][r] * rfac * cfv[ni];
        const float e = __expf(s);
        const bool match = (ctv[ni] == rty);
        if (diag) {
          if (gcolv[ni] != grow) { se += e; if (match) ps += s; }
        } else {
          se += e; if (match) ps += s;
          cse[ni] += e; if (match) cps[ni] += s;  // transpose -> row gcolv[ni]
        }
      }
      #pragma unroll
      for (int m = 8; m; m >>= 1) {
        se += __shfl_xor(se, m);
        ps += __shfl_xor(ps, m);
      }
      if (csub == 0) {
        atomicAdd(&sum_exp[grow], se);
        atomicAdd(&pos_sum[grow], ps);
      }
    }
  }

  if (!diag) {
    #pragma unroll
    for (int ni = 0; ni < 4; ++ni) {
      float se = cse[ni], ps = cps[ni];
      se += __shfl_xor(se, 16); se += __shfl_xor(se, 32);
      ps += __shfl_xor(ps, 16); ps += __shfl_xor(ps, 32);
      if (lane < 16) {
        atomicAdd(&sum_exp[gcolv[ni]], se);
        atomicAdd(&pos_sum[gcolv[ni]], ps);
      }
    }
  }
}

__global__ __launch_bounds__(1024) void k_final(
    const float* __restrict__ sum_exp, const float* __restrict__ pos_sum,
    const int* __restrict__ types, float* __restrict__ out) {
  const int t = threadIdx.x;
  __shared__ int h[32];
  if (t < 32) h[t] = 0;
  __syncthreads();
  int ty[8];
  #pragma unroll
  for (int i = 0; i < 8; ++i) {
    ty[i] = types[t + i * 1024];
    atomicAdd(&h[ty[i]], 1);
  }
  __syncthreads();
  float ls = 0.f, cnt = 0.f;
  #pragma unroll
  for (int i = 0; i < 8; ++i) {
    const int r = t + i * 1024;
    const int pc = h[ty[i]] - 1;
    if (pc > 0) {
      const float pm = pos_sum[r] / (float)pc;
      ls += -logf(__expf(pm) / sum_exp[r] + 1e-10f);
      cnt += 1.f;
    }
  }
  #pragma unroll
  for (int m = 32; m; m >>= 1) {
    ls += __shfl_xor(ls, m);
    cnt += __shfl_xor(cnt, m);
  }
  __shared__ float s1[16], s2[16];
  if ((t & 63) == 0) { s1[t >> 6] = ls; s2[t >> 6] = cnt; }
  __syncthreads();
  if (t == 0) {
    float T = 0.f, C = 0.f;
    for (int i = 0; i < 16; ++i) { T += s1[i]; C += s2[i]; }
    out[0] = (C > 0.f) ? T / C : 0.f;
  }
}

extern "C" void kernel_launch(void* const* d_in, const int* in_sizes, int n_in,
                              void* d_out, int out_size, void* d_ws, size_t ws_size,
                              hipStream_t stream) {
  const float* feat = (const float*)d_in[0];
  const long long* et = (const long long*)d_in[1];
  char* ws = (char*)d_ws;
  signed char* q8 = (signed char*)(ws + OFF_Q8);
  float* sum_e  = (float*)(ws + OFF_SUME);
  float* pos_s  = (float*)(ws + OFF_POSS);
  int* types    = (int*)(ws + OFF_TYPE);
  float* scale  = (float*)(ws + OFF_SCALE);
  float* out    = (float*)d_out;

  k_norm<<<N / 4, 256, 0, stream>>>(feat, et, q8, scale, types, sum_e, pos_s);
  k_gemm<<<NTRI, 256, 0, stream>>>(q8, scale, types, sum_e, pos_s);
  k_final<<<1, 1024, 0, stream>>>(sum_e, pos_s, types, out);
}

// Round 12
// 111.650 us; speedup vs baseline: 1.0906x; 1.0906x over previous
//
#include <hip/hip_runtime.h>
#include <hip/hip_bf16.h>

typedef unsigned short u16;
typedef __attribute__((ext_vector_type(4))) int   i32x4;
typedef __attribute__((ext_vector_type(4))) float f32x4;

constexpr int N = 8192;
constexpr int D = 1024;
constexpr float INVT = 1.0f / 0.07f;
constexpr int BK = 64;                         // i8 k per tile
constexpr int KT = D / BK;                     // 16 K-tiles
constexpr int NBLK = 64;                       // 8192 / 128 row-blocks
constexpr int NTRI = NBLK * (NBLK + 1) / 2;    // 2080 lower-tri tiles
constexpr int PANEL_BYTES = 128 * 1024;        // 128 rows x 1024 i8

// ---- workspace layout (bytes) ----
// q8 is stored TILED: panel p (128 rows), slot s (16 i8 of k), row r:
//   byte = p*131072 + s*2048 + r*16 -> MFMA fragments are directly
//   coalesced global loads (256B per 16-lane group).
constexpr size_t OFF_Q8    = 0;                      // N*D i8 = 8 MiB (tiled)
constexpr size_t OFF_SUME  = 8388608;                // N f32 (32 KiB)
constexpr size_t OFF_POSS  = OFF_SUME + 32768;       // N f32
constexpr size_t OFF_TYPE  = OFF_POSS + 32768;       // N i32
constexpr size_t OFF_SCALE = OFF_TYPE + 32768;       // N f32

// one wave per row: normalize, per-row absmax, quantize to i8 into the
// TILED q8 layout. Also zeroes sum_exp/pos_sum (replaces k_zero).
__global__ __launch_bounds__(256) void k_norm(
    const float* __restrict__ feat, const long long* __restrict__ et,
    signed char* __restrict__ q8, float* __restrict__ scales,
    int* __restrict__ types,
    float* __restrict__ sum_exp, float* __restrict__ pos_sum) {
  if (threadIdx.x < 4)
    sum_exp[blockIdx.x * 4 + threadIdx.x] = 0.f;
  else if (threadIdx.x < 8)
    pos_sum[blockIdx.x * 4 + threadIdx.x - 4] = 0.f;

  const int row = blockIdx.x * 4 + (threadIdx.x >> 6);
  const int l = threadIdx.x & 63;
  const float4* src = (const float4*)(feat + (size_t)row * D);
  float4 v[4];
  float ss = 0.f, ma = 0.f;
  #pragma unroll
  for (int c = 0; c < 4; ++c) {
    v[c] = src[c * 64 + l];
    ss += v[c].x * v[c].x + v[c].y * v[c].y + v[c].z * v[c].z + v[c].w * v[c].w;
    ma = fmaxf(ma, fmaxf(fmaxf(fabsf(v[c].x), fabsf(v[c].y)),
                         fmaxf(fabsf(v[c].z), fabsf(v[c].w))));
  }
  #pragma unroll
  for (int m = 32; m; m >>= 1) {
    ss += __shfl_xor(ss, m);
    ma = fmaxf(ma, __shfl_xor(ma, m));
  }
  const float sc = 1.0f / fmaxf(sqrtf(ss), 1e-12f);
  const float man = ma * sc;                       // normalized row absmax
  const float invq = 127.0f / fmaxf(man, 1e-30f);  // f_norm -> i8
  const float qf = sc * invq;
  // tiled write: word w = c*64+l (k-ints) -> slot s = w>>2, byte (w&3)*4.
  signed char* pb = q8 + (size_t)(row >> 7) * PANEL_BYTES + (row & 127) * 16;
  #pragma unroll
  for (int c = 0; c < 4; ++c) {
    const int b0 = (unsigned char)(signed char)__float2int_rn(v[c].x * qf);
    const int b1 = (unsigned char)(signed char)__float2int_rn(v[c].y * qf);
    const int b2 = (unsigned char)(signed char)__float2int_rn(v[c].z * qf);
    const int b3 = (unsigned char)(signed char)__float2int_rn(v[c].w * qf);
    const int w = c * 64 + l;
    *(int*)(pb + (w >> 2) * 2048 + (w & 3) * 4) =
        b0 | (b1 << 8) | (b2 << 16) | (b3 << 24);
  }
  if (l == 0) {
    scales[row] = man / 127.0f;                    // sim = acc*s_i*s_j
    types[row] = (int)et[row];
  }
}

__device__ __forceinline__ void mfma_i8v(i32x4& d, i32x4 a, i32x4 b) {
  asm volatile("v_mfma_i32_16x16x64_i8 %0, %1, %2, %0"
               : "+v"(d) : "v"(a), "v"(b));
}

// 128x128 lower-tri tiles of sim = (q8 . q8^T) * s_i * s_j / T.
// r10's barrier-free register K-loop, with a CHUNKED L2-resident XCD
// mapping. Old mapping pinned B-panels but STREAMED A-panels from L3
// (8MB q8 > 4MB per-XCD L2): ~900-2000cy loaded latency vs ~750cy of
// 3-wave MFMA cover -- the invariant wall of r5-r10 (FETCH 31MB = A
// re-read ~4x). New mapping: Latin-square cb ownership (XCD x owns
// cb = 8j+((j+x)&7)), enumerated in rb-BANDS of 8: per band the XCD
// touches 8 A-panels + <=8 B-panels = 2MB < 4MB L2, each reused ~8x
// from L2 (~250cy) -> latency now within wave-level cover. Perfectly
// balanced: 260 tiles/XCD, closed-form decode.
__global__ __launch_bounds__(256) void k_gemm(
    const signed char* __restrict__ q8, const float* __restrict__ scales,
    const int* __restrict__ types,
    float* __restrict__ sum_exp, float* __restrict__ pos_sum) {
  __shared__ int rt[128], ct[128];
  __shared__ float rsl[128], csl[128];

  // ---- chunked tile decode ----
  const int pid = blockIdx.x;
  const int x = pid & 7;                  // XCD (HW round-robins pid%8)
  int l = pid >> 3;                       // 0..259 local index
  int b = 0, p = 0;
  for (;;) {                              // find rb-band b
    p = (b + x) & 7;
    const int nb = 8 * b + 8 - p;         // tiles of this XCD in band b
    if (l < nb) break;
    l -= nb; ++b;
  }
  int j = 0;
  for (;;) {                              // find owned-cb slot j within band
    const int cnt = (j == b) ? (8 - p) : 8;
    if (l < cnt) break;
    l -= cnt; ++j;
  }
  const int cb = 8 * j + ((j + x) & 7);
  const int rb = 8 * b + ((j == b) ? (p + l) : l);

  const int brow = rb * 128, bcol = cb * 128;
  const bool diag = (rb == cb);

  const int tid = threadIdx.x;
  const int lane = tid & 63;
  const int wid = tid >> 6;
  const int wr = wid >> 1, wc = wid & 1;

  if (tid < 128) {
    rt[tid] = types[brow + tid];
    rsl[tid] = scales[brow + tid] * INVT;   // fold 1/T into row scale
  } else {
    ct[tid - 128] = types[bcol + tid - 128];
    csl[tid - 128] = scales[bcol + tid - 128];
  }
  __syncthreads();                          // tables published; last barrier

  i32x4 acc[4][4];
  #pragma unroll
  for (int i = 0; i < 4; ++i)
    #pragma unroll
    for (int jj = 0; jj < 4; ++jj) acc[i][jj] = (i32x4){0, 0, 0, 0};

  // fragment base: lane supplies row (lane&15) of its sub-tile, k-slot
  // lane>>4; global byte = panel + (slot*128 + row)*16 (+ mi*16 rows).
  const int slotR = lane >> 4;
  const int arow = wr * 64 + (lane & 15);
  const int brw  = wc * 64 + (lane & 15);
  const signed char* pA =
      q8 + (size_t)rb * PANEL_BYTES + (slotR * 128 + arow) * 16;
  const signed char* pB =
      q8 + (size_t)cb * PANEL_BYTES + (slotR * 128 + brw) * 16;

  i32x4 a0[4], b0[4], a1[4], b1[4];

  #define LOADP(tt, A, B) {                                           \
    const int o = (tt) * 8192;                                        \
    _Pragma("unroll")                                                 \
    for (int q = 0; q < 4; ++q) {                                     \
      A[q] = *(const i32x4*)(pA + o + q * 256);                       \
      B[q] = *(const i32x4*)(pB + o + q * 256);                       \
    } }

  #define MFMAP(A, B) {                                               \
    __builtin_amdgcn_s_setprio(1);                                    \
    _Pragma("unroll")                                                 \
    for (int mi = 0; mi < 4; ++mi)                                    \
      _Pragma("unroll")                                               \
      for (int ni = 0; ni < 4; ++ni) mfma_i8v(acc[mi][ni], A[mi], B[ni]); \
    __builtin_amdgcn_s_setprio(0);                                    \
  }

  LOADP(0, a0, b0)
  LOADP(1, a1, b1)
  for (int t = 0; t < KT; t += 2) {
    MFMAP(a0, b0)
    if (t + 2 < KT) LOADP(t + 2, a0, b0)   // overwrite after consumption
    MFMAP(a1, b1)
    if (t + 3 < KT) LOADP(t + 3, a1, b1)
  }

  // MFMA -> VALU read hazard guard (inline-asm MFMA opaque to hazard recog.)
  asm volatile("s_nop 7\n\ts_nop 7\n\ts_nop 7");
  #pragma unroll
  for (int i = 0; i < 4; ++i)
    #pragma unroll
    for (int jj = 0; jj < 4; ++jj) asm volatile("" : "+v"(acc[i][jj]));

  // epilogue: C/D layout col = lane&15, row = (lane>>4)*4 + reg  [m89]
  const int csub = lane & 15;
  const int rsub = (lane >> 4) * 4;
  int gcolv[4], ctv[4];
  float cfv[4];
  #pragma unroll
  for (int ni = 0; ni < 4; ++ni) {
    const int cl = wc * 64 + ni * 16 + csub;
    gcolv[ni] = bcol + cl;
    ctv[ni] = ct[cl];
    cfv[ni] = csl[cl];
  }
  float cse[4] = {0.f, 0.f, 0.f, 0.f};
  float cps[4] = {0.f, 0.f, 0.f, 0.f};

  #pragma unroll
  for (int mi = 0; mi < 4; ++mi) {
    #pragma unroll
    for (int r = 0; r < 4; ++r) {
      const int rl = wr * 64 + mi * 16 + rsub + r;
      const int grow = brow + rl;
      const int rty = rt[rl];
      const float rfac = rsl[rl];                 // includes 1/T
      float se = 0.f, ps = 0.f;
      #pragma unroll
      for (int ni = 0; ni < 4; ++ni) {
        const float s = (float)acc[mi][ni][r] * rfac * cfv[ni];
        const float e = __expf(s);
        const bool match = (ctv[ni] == rty);
        if (diag) {
          if (gcolv[ni] != grow) { se += e; if (match) ps += s; }
        } else {
          se += e; if (match) ps += s;
          cse[ni] += e; if (match) cps[ni] += s;  // transpose -> row gcolv[ni]
        }
      }
      #pragma unroll
      for (int m = 8; m; m >>= 1) {
        se += __shfl_xor(se, m);
        ps += __shfl_xor(ps, m);
      }
      if (csub == 0) {
        atomicAdd(&sum_exp[grow], se);
        atomicAdd(&pos_sum[grow], ps);
      }
    }
  }

  if (!diag) {
    #pragma unroll
    for (int ni = 0; ni < 4; ++ni) {
      float se = cse[ni], ps = cps[ni];
      se += __shfl_xor(se, 16); se += __shfl_xor(se, 32);
      ps += __shfl_xor(ps, 16); ps += __shfl_xor(ps, 32);
      if (lane < 16) {
        atomicAdd(&sum_exp[gcolv[ni]], se);
        atomicAdd(&pos_sum[gcolv[ni]], ps);
      }
    }
  }
}

__global__ __launch_bounds__(1024) void k_final(
    const float* __restrict__ sum_exp, const float* __restrict__ pos_sum,
    const int* __restrict__ types, float* __restrict__ out) {
  const int t = threadIdx.x;
  __shared__ int h[32];
  if (t < 32) h[t] = 0;
  __syncthreads();
  int ty[8];
  #pragma unroll
  for (int i = 0; i < 8; ++i) {
    ty[i] = types[t + i * 1024];
    atomicAdd(&h[ty[i]], 1);
  }
  __syncthreads();
  float ls = 0.f, cnt = 0.f;
  #pragma unroll
  for (int i = 0; i < 8; ++i) {
    const int r = t + i * 1024;
    const int pc = h[ty[i]] - 1;
    if (pc > 0) {
      const float pm = pos_sum[r] / (float)pc;
      ls += -logf(__expf(pm) / sum_exp[r] + 1e-10f);
      cnt += 1.f;
    }
  }
  #pragma unroll
  for (int m = 32; m; m >>= 1) {
    ls += __shfl_xor(ls, m);
    cnt += __shfl_xor(cnt, m);
  }
  __shared__ float s1[16], s2[16];
  if ((t & 63) == 0) { s1[t >> 6] = ls; s2[t >> 6] = cnt; }
  __syncthreads();
  if (t == 0) {
    float T = 0.f, C = 0.f;
    for (int i = 0; i < 16; ++i) { T += s1[i]; C += s2[i]; }
    out[0] = (C > 0.f) ? T / C : 0.f;
  }
}

extern "C" void kernel_launch(void* const* d_in, const int* in_sizes, int n_in,
                              void* d_out, int out_size, void* d_ws, size_t ws_size,
                              hipStream_t stream) {
  const float* feat = (const float*)d_in[0];
  const long long* et = (const long long*)d_in[1];
  char* ws = (char*)d_ws;
  signed char* q8 = (signed char*)(ws + OFF_Q8);
  float* sum_e  = (float*)(ws + OFF_SUME);
  float* pos_s  = (float*)(ws + OFF_POSS);
  int* types    = (int*)(ws + OFF_TYPE);
  float* scale  = (float*)(ws + OFF_SCALE);
  float* out    = (float*)d_out;

  k_norm<<<N / 4, 256, 0, stream>>>(feat, et, q8, scale, types, sum_e, pos_s);
  k_gemm<<<NTRI, 256, 0, stream>>>(q8, scale, types, sum_e, pos_s);
  k_final<<<1, 1024, 0, stream>>>(sum_e, pos_s, types, out);
}